// Round 21
// baseline (334.982 us; speedup 1.0000x reference)
//
#include <hip/hip_runtime.h>
#include <hip/hip_bf16.h>
#include <math.h>

// BayesianSkipgram: V=100000, E=256, D=128, B=8192, C=10
// v21: SINGLE kernel, block-role split (removes 2 device-drain boundaries):
//   blocks 0..1023  = producers (v15 bsg_h verbatim, BT=8). Blocks 0..47
//                     additionally fold in k_cvt (1 float4/thread) and bump
//                     flg[0]; producers spin for flg[0]==48 AFTER issuing
//                     their 12 gather loads (spin hides under gather latency).
//   blocks 1024..1279 = consumers (v15 bsg_kl verbatim, BT=32); consumer cid
//                     waits on producer flags 4cid..4cid+3, then overlaps its
//                     UW-GEMM+KL with remaining producers.
// Sync: flags zeroed per call via hipMemsetAsync (deterministic); producer:
// stores -> __syncthreads (vmcnt drain) -> tid0 __threadfence (L2 wb) ->
// device-scope flag store. Consumer: tid0 relaxed spin + s_sleep -> barrier
// -> __threadfence (inv) -> read. Deadlock-free: 768 resident >> 256
// consumers => >=512 producer slots always; producers never wait on consumers.
// ws (ushort): M_bf [0,32768) U|W_bf [32768,98304) h [98304,2195456)
//             flags int[1025] @ byte 4390912. Needs >= 4,395,012 B.

#define CTXN  10
#define DDIM  128
#define WS_M   0
#define WS_UW  32768
#define WS_H   98304
#define FLG_BYTE 4390912

#define NPROD 1024
#define BT1   8
#define ROWSP 96              // rows r = c*8+b (c=0..10); 88..95 garbage
#define LP2   264             // A row stride (ushort): 528 B, 2-way alias (free)
#define BT2   32
#define HLP   264

typedef short bf16x8 __attribute__((ext_vector_type(8)));
typedef float f32x4  __attribute__((ext_vector_type(4)));

__device__ __forceinline__ uint2 cvt4(float4 v) {
    union { __hip_bfloat162 h2; unsigned u; } a, b;
    a.h2 = __float22bfloat162_rn(make_float2(v.x, v.y));
    b.h2 = __float22bfloat162_rn(make_float2(v.z, v.w));
    return make_uint2(a.u, b.u);
}

__device__ __forceinline__ float softplusf(float v) {
    return fmaxf(v, 0.0f) + log1pf(expf(-fabsf(v)));
}

__global__ __launch_bounds__(512, 4) void bsg_all(
    const int* __restrict__ x, const int* __restrict__ ctx,
    const float* __restrict__ W_emb, const float* __restrict__ M_w,
    const float* __restrict__ M_b,   const float* __restrict__ U_w,
    const float* __restrict__ U_b,   const float* __restrict__ W_w,
    const float* __restrict__ W_b,   const float* __restrict__ pmu,
    const float* __restrict__ psg,   unsigned short* __restrict__ ws,
    float* __restrict__ out)
{
    __shared__ __align__(16) unsigned short sm[ROWSP * LP2];   // 50688 B (both roles)
    __shared__ int   idx_s[ROWSP];
    __shared__ float P_s[BT2 * 8];

    int* flg = (int*)((char*)ws + FLG_BYTE);   // [0]=cvt count, [1+pb]=producer done

    const int tid  = threadIdx.x;
    const int bid  = blockIdx.x;
    const int w    = tid >> 6;
    const int lane = tid & 63;
    const int l15  = lane & 15;
    const int lg   = lane >> 4;

    if (bid < NPROD) {
        // ================= producer: gather + emb@M_w^T + relu-sum -> h ====
        const int b0 = bid * BT1;

        // ---- k_cvt fold: blocks 0..47, exactly 1 float4 per thread ----
        if (bid < 48) {
            int it = bid * 512 + tid;            // 0..24575
            int which = it >> 13, i = it & 8191; // 0:M 1:U 2:W
            const float* src = (which == 0) ? M_w : (which == 1) ? U_w : W_w;
            float4 v = ((const float4*)src)[i];
            *(uint2*)&ws[which * 32768 + i * 4] = cvt4(v);
            __syncthreads();                     // block's cvt stores drained
            if (tid == 0) { __threadfence(); atomicAdd(&flg[0], 1); }
        }

        if (tid < ROWSP) {
            int c = tid >> 3, b = b0 + (tid & 7);
            idx_s[tid] = (c >= 11) ? 0 : ((c == 0) ? x[b] : ctx[b * CTXN + (c - 1)]);
        }
        __syncthreads();

        // ---- single-shot staging: 12 wave-per-row coalesced 1KB loads ----
        const int rs = tid >> 6;
        const int qs = tid & 63;
        const float4* We = (const float4*)W_emb;
        float4 rr[12];
#pragma unroll
        for (int s = 0; s < 12; ++s)
            rr[s] = We[(size_t)idx_s[rs + 8 * s] * 64 + qs];

        // ---- wait for cvt (overlaps gather latency), then acquire ----
        if (tid == 0)
            while (__hip_atomic_load(&flg[0], __ATOMIC_RELAXED,
                                     __HIP_MEMORY_SCOPE_AGENT) < 48)
                __builtin_amdgcn_s_sleep(2);
        __syncthreads();
        __threadfence();                         // inv: M_bf reads see cvt data

#pragma unroll
        for (int s = 0; s < 12; ++s)
            *(uint2*)&sm[(rs + 8 * s) * LP2 + 4 * qs] = cvt4(rr[s]);
        __syncthreads();                         // staging barrier

        // ---- MFMA: 4 k-chunks x 6 M-tiles, M-frags from L2-hot bf16 ws ----
        const unsigned short* Mb_bf = ws + WS_M;
        const int mrow = 16 * w + l15;
        f32x4 acc[6] = {};
#pragma unroll
        for (int ch = 0; ch < 4; ++ch) {
            bf16x8 m0 = *(const bf16x8*)&Mb_bf[mrow * 256 + 64 * ch + 8 * lg];
            bf16x8 m1 = *(const bf16x8*)&Mb_bf[mrow * 256 + 64 * ch + 32 + 8 * lg];
#pragma unroll
            for (int mt = 0; mt < 6; ++mt) {
                bf16x8 a0 = *(const bf16x8*)&sm[(16 * mt + l15) * LP2 + 64 * ch + 8 * lg];
                bf16x8 a1 = *(const bf16x8*)&sm[(16 * mt + l15) * LP2 + 64 * ch + 32 + 8 * lg];
                acc[mt] = __builtin_amdgcn_mfma_f32_16x16x32_bf16(a0, m0, acc[mt], 0, 0, 0);
                acc[mt] = __builtin_amdgcn_mfma_f32_16x16x32_bf16(a1, m1, acc[mt], 0, 0, 0);
            }
        }

        // relu-sum: lane row = 16mt+4lg+q; c = row>>3, b = row&7.
        const int dg = 16 * w + l15;
        const float mb = M_b[dg];
        float p1[4] = {0, 0, 0, 0}, p2[4] = {0, 0, 0, 0};
#pragma unroll
        for (int mt = 0; mt < 6; ++mt) {
#pragma unroll
            for (int q = 0; q < 4; ++q) {
                float r = fmaxf(acc[mt][q] + mb, 0.0f);
                if (lg < 2) { if (mt == 0) p1[q] = r; else p2[q] += r; }
                else        { if (mt < 5)  p2[q] += r; }
            }
        }
        unsigned short* hws = ws + WS_H;
#pragma unroll
        for (int q = 0; q < 4; ++q) {
            float other = __shfl_xor(p2[q], 32);
            if (lg < 2) {
                int b = 4 * lg + q;
                __hip_bfloat16 t1 = __float2bfloat16(10.0f * p1[q]);
                __hip_bfloat16 t2 = __float2bfloat16(p2[q] + other);
                hws[(size_t)(b0 + b) * 256 + dg]       = *(unsigned short*)&t1;
                hws[(size_t)(b0 + b) * 256 + 128 + dg] = *(unsigned short*)&t2;
            }
        }
        __syncthreads();                         // all h stores drained (vmcnt)
        if (tid == 0) {
            __threadfence();                     // XCD L2 writeback
            __hip_atomic_store(&flg[1 + bid], 1, __ATOMIC_RELAXED,
                               __HIP_MEMORY_SCOPE_AGENT);
        }
    } else {
        // ================= consumer: h @ [U;W]^T + softplus + KL ============
        const int cid = bid - NPROD;
        const int b0  = cid * BT2;
        const int d   = 16 * w + l15;

        // prior gathers issued upfront (no flag dependency)
        float pm[2][4], ps[2][4];
#pragma unroll
        for (int mt = 0; mt < 2; ++mt)
#pragma unroll
            for (int q = 0; q < 4; ++q) {
                int xb = x[b0 + 16 * mt + 4 * lg + q];
                pm[mt][q] = pmu[(size_t)xb * DDIM + d];
                ps[mt][q] = psg[(size_t)xb * DDIM + d];
            }

        // wait for the 4 producers of rows [32cid, 32cid+32)
        if (tid == 0) {
#pragma unroll
            for (int k = 0; k < 4; ++k)
                while (__hip_atomic_load(&flg[1 + 4 * cid + k], __ATOMIC_RELAXED,
                                         __HIP_MEMORY_SCOPE_AGENT) == 0)
                    __builtin_amdgcn_s_sleep(2);
        }
        __syncthreads();
        __threadfence();                         // inv: h reads see fresh data

        // h tile copy: 512 threads x 2 x 16B = whole [32][256] tile
        unsigned short* H_s = sm;
        const unsigned short* hws = ws + WS_H;
#pragma unroll
        for (int s = 0; s < 2; ++s) {
            int it = tid + 512 * s;
            int r = it >> 5, q = it & 31;
            *(uint4*)&H_s[r * HLP + 8 * q] =
                *(const uint4*)&hws[(size_t)(b0 + r) * 256 + 8 * q];
        }
        __syncthreads();

        const unsigned short* UWb = ws + WS_UW;  // [256][256]: 0..127=U, 128..255=W
        f32x4 acc2[2][2] = {};
#pragma unroll
        for (int ks = 0; ks < 8; ++ks) {
            bf16x8 bu = *(const bf16x8*)&UWb[d * 256 + 32 * ks + 8 * lg];
            bf16x8 bw = *(const bf16x8*)&UWb[(128 + d) * 256 + 32 * ks + 8 * lg];
#pragma unroll
            for (int mt = 0; mt < 2; ++mt) {
                bf16x8 hf = *(const bf16x8*)&H_s[(16 * mt + l15) * HLP + 32 * ks + 8 * lg];
                acc2[mt][0] = __builtin_amdgcn_mfma_f32_16x16x32_bf16(hf, bu, acc2[mt][0], 0, 0, 0);
                acc2[mt][1] = __builtin_amdgcn_mfma_f32_16x16x32_bf16(hf, bw, acc2[mt][1], 0, 0, 0);
            }
        }

        const float ub = U_b[d], wb = W_b[d];
#pragma unroll
        for (int mt = 0; mt < 2; ++mt) {
#pragma unroll
            for (int q = 0; q < 4; ++q) {
                int rb = 16 * mt + 4 * lg + q;
                float mu = acc2[mt][0][q] + ub;
                float sg = softplusf(acc2[mt][1][q] + wb);
                float dm = mu - pm[mt][q];
                float p  = ps[mt][q] / sg + dm * dm / sg + logf(sg) - logf(ps[mt][q]);
                p += __shfl_xor(p, 1);
                p += __shfl_xor(p, 2);
                p += __shfl_xor(p, 4);
                p += __shfl_xor(p, 8);
                if (l15 == 0) P_s[rb * 8 + w] = p;
            }
        }
        __syncthreads();
        if (tid < BT2) {
            float s = 0.0f;
#pragma unroll
            for (int k = 0; k < 8; ++k) s += P_s[tid * 8 + k];
            out[b0 + tid] = 0.5f * (s - (float)DDIM);
        }
    }
}

extern "C" void kernel_launch(void* const* d_in, const int* in_sizes, int n_in,
                              void* d_out, int out_size, void* d_ws, size_t ws_size,
                              hipStream_t stream) {
    const int*   x     = (const int*)  d_in[0];
    const int*   ctx   = (const int*)  d_in[1];
    const float* W_emb = (const float*)d_in[2];
    const float* M_w   = (const float*)d_in[3];
    const float* M_b   = (const float*)d_in[4];
    const float* U_w   = (const float*)d_in[5];
    const float* U_b   = (const float*)d_in[6];
    const float* W_w   = (const float*)d_in[7];
    const float* W_b   = (const float*)d_in[8];
    const float* pmu   = (const float*)d_in[9];
    const float* psg   = (const float*)d_in[10];
    float* out = (float*)d_out;
    unsigned short* ws = (unsigned short*)d_ws;   // needs >= 4,395,012 bytes

    hipMemsetAsync((char*)d_ws + FLG_BYTE, 0, (1 + NPROD) * sizeof(int), stream);
    bsg_all<<<dim3(NPROD + 8192 / BT2), dim3(512), 0, stream>>>(
        x, ctx, W_emb, M_w, M_b, U_w, U_b, W_w, W_b, pmu, psg, ws, out);
}

// Round 22
// 41.391 us; speedup vs baseline: 8.0932x; 8.0932x over previous
//
#include <hip/hip_runtime.h>
#include <hip/hip_bf16.h>
#include <math.h>

// BayesianSkipgram: V=100000, E=256, D=128, B=8192, C=10
// FINAL (v15 champion @ 41.50us, reproduced 41.54): three kernels.
//   k_cvt : M_w/U_w/W_w fp32 -> bf16 into ws (192 KB).
//   bsg_h : gathered emb @ M_w^T + relu-sum -> h[8192,256] bf16 in ws.
//           BT=8, 512 thr, 1024 blocks (3/CU, LDS-limited). Single-shot
//           staging: 12 wave-per-row coalesced 1KB loads upfront (max MLP),
//           ONE barrier; M-frags loaded in-loop from L2-hot bf16 panel.
//   bsg_kl: h @ [U;W]^T + softplus + prior-gather + KL. BT=32 (256 blocks),
//           2 M-tiles/wave, priors hoisted to kernel start.
// Rejected by experiment: fusion (46-49), vocab-precompute (54), reg-direct
// gather (74), fp32 weight paths (44-52), BT1=4/16 (46), deeper pipelines
// (42-48), mreg hoist (44), producer-consumer flag sync (335).
// ws layout (ushort): M_bf [0,32768), U|W_bf [32768,98304), h [98304,+2M).

#define CTXN  10
#define DDIM  128
#define WS_M   0
#define WS_UW  32768
#define WS_H   98304

typedef short bf16x8 __attribute__((ext_vector_type(8)));
typedef float f32x4  __attribute__((ext_vector_type(4)));

__device__ __forceinline__ uint2 cvt4(float4 v) {
    union { __hip_bfloat162 h2; unsigned u; } a, b;
    a.h2 = __float22bfloat162_rn(make_float2(v.x, v.y));
    b.h2 = __float22bfloat162_rn(make_float2(v.z, v.w));
    return make_uint2(a.u, b.u);
}

__device__ __forceinline__ float softplusf(float v) {
    return fmaxf(v, 0.0f) + log1pf(expf(-fabsf(v)));
}

// ---------------- kernel 0: weight fp32 -> bf16 ----------------
__global__ __launch_bounds__(256) void k_cvt(
    const float* __restrict__ M_w, const float* __restrict__ U_w,
    const float* __restrict__ W_w, unsigned short* __restrict__ ws)
{
    int which = blockIdx.x >> 5;                       // 0:M 1:U 2:W
    int i = ((blockIdx.x & 31) << 8) | threadIdx.x;    // float4 idx 0..8191
    const float* src = (which == 0) ? M_w : (which == 1) ? U_w : W_w;
    float4 v = ((const float4*)src)[i];
    *(uint2*)&ws[which * 32768 + i * 4] = cvt4(v);
}

// ---------------- kernel 1: gather + emb@M_w^T + relu-sum -> h ----------------
#define BT1   8
#define ROWSP 96              // LDS rows 0..87 staged (r = c*8+b); 88..95 garbage
#define LP2   264             // A row stride (ushort): 528 B -> 2-way bank alias (free)

__global__ __launch_bounds__(512, 4) void bsg_h(
    const int* __restrict__ x, const int* __restrict__ ctx,
    const float* __restrict__ W_emb, const float* __restrict__ M_b,
    const unsigned short* __restrict__ wsr, unsigned short* __restrict__ hws)
{
    __shared__ __align__(16) unsigned short A_s[ROWSP * LP2];   // 50688 B
    __shared__ int idx_s[ROWSP];

    const int tid  = threadIdx.x;
    const int b0   = blockIdx.x * BT1;
    const int w    = tid >> 6;       // wave 0..7 owns d-cols 16w..16w+15
    const int lane = tid & 63;
    const int l15  = lane & 15;
    const int lg   = lane >> 4;

    if (tid < ROWSP) {
        int c = tid >> 3, b = b0 + (tid & 7);
        idx_s[tid] = (c >= 11) ? 0 : ((c == 0) ? x[b] : ctx[b * CTXN + (c - 1)]);
    }
    __syncthreads();

    // ---- single-shot staging: 12 steps, wave-per-row perfect coalescing ----
    const int rs = tid >> 6;
    const int qs = tid & 63;
    const float4* We = (const float4*)W_emb;

    float4 rr[12];
#pragma unroll
    for (int s = 0; s < 12; ++s)
        rr[s] = We[(size_t)idx_s[rs + 8 * s] * 64 + qs];
#pragma unroll
    for (int s = 0; s < 12; ++s)
        *(uint2*)&A_s[(rs + 8 * s) * LP2 + 4 * qs] = cvt4(rr[s]);
    __syncthreads();   // the only phase-1 barrier

    // ---- MFMA: 4 k-chunks x 6 M-tiles, M-frags from L2-hot bf16 ws ----
    const unsigned short* Mb_bf = wsr + WS_M;   // [128][256] bf16
    const int mrow = 16 * w + l15;
    f32x4 acc[6] = {};
#pragma unroll
    for (int ch = 0; ch < 4; ++ch) {
        bf16x8 m0 = *(const bf16x8*)&Mb_bf[mrow * 256 + 64 * ch + 8 * lg];
        bf16x8 m1 = *(const bf16x8*)&Mb_bf[mrow * 256 + 64 * ch + 32 + 8 * lg];
#pragma unroll
        for (int mt = 0; mt < 6; ++mt) {
            bf16x8 a0 = *(const bf16x8*)&A_s[(16 * mt + l15) * LP2 + 64 * ch + 8 * lg];
            bf16x8 a1 = *(const bf16x8*)&A_s[(16 * mt + l15) * LP2 + 64 * ch + 32 + 8 * lg];
            acc[mt] = __builtin_amdgcn_mfma_f32_16x16x32_bf16(a0, m0, acc[mt], 0, 0, 0);
            acc[mt] = __builtin_amdgcn_mfma_f32_16x16x32_bf16(a1, m1, acc[mt], 0, 0, 0);
        }
    }

    // relu-sum: lane row = 16mt+4lg+q; c = row>>3, b = row&7.
    // lg<2 -> even slots (c=2mt), lg>=2 -> odd slots (c=2mt+1; mt=5 -> pad).
    const int dg = 16 * w + l15;
    const float mb = M_b[dg];
    float p1[4] = {0, 0, 0, 0}, p2[4] = {0, 0, 0, 0};
#pragma unroll
    for (int mt = 0; mt < 6; ++mt) {
#pragma unroll
        for (int q = 0; q < 4; ++q) {
            float r = fmaxf(acc[mt][q] + mb, 0.0f);
            if (lg < 2) { if (mt == 0) p1[q] = r; else p2[q] += r; }
            else        { if (mt < 5)  p2[q] += r; }
        }
    }
#pragma unroll
    for (int q = 0; q < 4; ++q) {
        float other = __shfl_xor(p2[q], 32);     // pair lg0<->lg2, lg1<->lg3
        if (lg < 2) {
            int b = 4 * lg + q;
            __hip_bfloat16 t1 = __float2bfloat16(10.0f * p1[q]);   // C*relu(Rw)
            __hip_bfloat16 t2 = __float2bfloat16(p2[q] + other);   // sum relu(Rc)
            hws[(size_t)(b0 + b) * 256 + dg]       = *(unsigned short*)&t1;
            hws[(size_t)(b0 + b) * 256 + 128 + dg] = *(unsigned short*)&t2;
        }
    }
}

// ---------------- kernel 2: h @ [U;W]^T + softplus + KL (BT2=32) ----------------
#define BT2  32
#define HLP  264

__global__ __launch_bounds__(512, 4) void bsg_kl(
    const int* __restrict__ x, const float* __restrict__ U_b,
    const float* __restrict__ W_b, const float* __restrict__ pmu,
    const float* __restrict__ psg, const unsigned short* __restrict__ wsr,
    float* __restrict__ out)
{
    __shared__ __align__(16) unsigned short H_s[BT2 * HLP];   // 16896 B
    __shared__ float P_s[BT2 * 8];

    const int tid  = threadIdx.x;
    const int b0   = blockIdx.x * BT2;
    const int w    = tid >> 6;       // wave 0..7 owns d-cols 16w..16w+15
    const int lane = tid & 63;
    const int l15  = lane & 15;
    const int lg   = lane >> 4;
    const int d    = 16 * w + l15;

    // prior gathers issued upfront (x[] L2-hot); consumed only in epilogue
    float pm[2][4], ps[2][4];
#pragma unroll
    for (int mt = 0; mt < 2; ++mt)
#pragma unroll
        for (int q = 0; q < 4; ++q) {
            int xb = x[b0 + 16 * mt + 4 * lg + q];
            pm[mt][q] = pmu[(size_t)xb * DDIM + d];
            ps[mt][q] = psg[(size_t)xb * DDIM + d];
        }

    // h tile copy: 512 threads x 2 x 16B = whole [32][256] tile
    const unsigned short* hws = wsr + WS_H;
#pragma unroll
    for (int s = 0; s < 2; ++s) {
        int it = tid + 512 * s;
        int r = it >> 5, q = it & 31;
        *(uint4*)&H_s[r * HLP + 8 * q] =
            *(const uint4*)&hws[(size_t)(b0 + r) * 256 + 8 * q];
    }
    __syncthreads();

    const unsigned short* UWb = wsr + WS_UW;    // [256][256]: 0..127=U, 128..255=W
    f32x4 acc2[2][2] = {};                      // [mtile][0=mu,1=presig]
#pragma unroll
    for (int ks = 0; ks < 8; ++ks) {
        bf16x8 bu = *(const bf16x8*)&UWb[d * 256 + 32 * ks + 8 * lg];
        bf16x8 bw = *(const bf16x8*)&UWb[(128 + d) * 256 + 32 * ks + 8 * lg];
#pragma unroll
        for (int mt = 0; mt < 2; ++mt) {
            bf16x8 hf = *(const bf16x8*)&H_s[(16 * mt + l15) * HLP + 32 * ks + 8 * lg];
            acc2[mt][0] = __builtin_amdgcn_mfma_f32_16x16x32_bf16(hf, bu, acc2[mt][0], 0, 0, 0);
            acc2[mt][1] = __builtin_amdgcn_mfma_f32_16x16x32_bf16(hf, bw, acc2[mt][1], 0, 0, 0);
        }
    }

    const float ub = U_b[d], wb = W_b[d];
#pragma unroll
    for (int mt = 0; mt < 2; ++mt) {
#pragma unroll
        for (int q = 0; q < 4; ++q) {
            int rb = 16 * mt + 4 * lg + q;      // batch row (C/D: row=4lg+q, col=l15)
            float mu = acc2[mt][0][q] + ub;
            float sg = softplusf(acc2[mt][1][q] + wb);
            float dm = mu - pm[mt][q];
            float p  = ps[mt][q] / sg + dm * dm / sg + logf(sg) - logf(ps[mt][q]);
            p += __shfl_xor(p, 1);
            p += __shfl_xor(p, 2);
            p += __shfl_xor(p, 4);
            p += __shfl_xor(p, 8);
            if (l15 == 0) P_s[rb * 8 + w] = p;
        }
    }
    __syncthreads();
    if (tid < BT2) {
        float s = 0.0f;
#pragma unroll
        for (int k = 0; k < 8; ++k) s += P_s[tid * 8 + k];
        out[b0 + tid] = 0.5f * (s - (float)DDIM);
    }
}

extern "C" void kernel_launch(void* const* d_in, const int* in_sizes, int n_in,
                              void* d_out, int out_size, void* d_ws, size_t ws_size,
                              hipStream_t stream) {
    const int*   x     = (const int*)  d_in[0];
    const int*   ctx   = (const int*)  d_in[1];
    const float* W_emb = (const float*)d_in[2];
    const float* M_w   = (const float*)d_in[3];
    const float* M_b   = (const float*)d_in[4];
    const float* U_w   = (const float*)d_in[5];
    const float* U_b   = (const float*)d_in[6];
    const float* W_w   = (const float*)d_in[7];
    const float* W_b   = (const float*)d_in[8];
    const float* pmu   = (const float*)d_in[9];
    const float* psg   = (const float*)d_in[10];
    float* out = (float*)d_out;
    unsigned short* ws = (unsigned short*)d_ws;   // needs >= 4,390,912 bytes

    k_cvt<<<dim3(96), dim3(256), 0, stream>>>(M_w, U_w, W_w, ws);
    bsg_h<<<dim3(8192 / BT1), dim3(512), 0, stream>>>(x, ctx, W_emb, M_b,
                                                      ws, ws + WS_H);
    bsg_kl<<<dim3(8192 / BT2), dim3(512), 0, stream>>>(x, U_b, W_b, pmu, psg,
                                                       ws, out);
}